// Round 4
// baseline (71.155 us; speedup 1.0000x reference)
//
#include <hip/hip_runtime.h>

#define N_PTS 20000
#define NA 20480            // candidates padded to 640 tiles of 32
#define NB 20032            // queries padded to 313 wave-groups of 64
#define TILES_TOTAL 640

typedef __attribute__((ext_vector_type(8))) short bf16x8;
typedef __attribute__((ext_vector_type(16))) float f32x16;

static __device__ __forceinline__ unsigned short f2bf(float f) {
    unsigned int u = __float_as_uint(f);
    unsigned int r = (u + 0x7FFFu + ((u >> 16) & 1u)) >> 16;   // RNE
    return (unsigned short)r;
}
static __device__ __forceinline__ float bf2f(unsigned short h) {
    return __uint_as_float(((unsigned int)h) << 16);
}

// single-instruction bitfield insert: (a & mask) | (b & ~mask)
static __device__ __forceinline__ unsigned bfi(unsigned mask, unsigned a, unsigned b) {
    unsigned d;
    asm("v_bfi_b32 %0, %1, %2, %3" : "=v"(d) : "v"(mask), "v"(a), "v"(b));
    return d;
}

// Build MFMA operand matrices.
// A row (candidate m), K=16 slots:
//   slots 0-2: -2*c_hi (pairs q_hi) | 3-5: -2*c_hi (pairs q_lo) | 6-8: -2*c_lo (pairs q_hi)
//   slots 9,10: y2 hi/lo (pair with 1.0)
// => acc ~= ||y||^2 - 2 x.y  (argmin key; x^2 constant per query)
__global__ __launch_bounds__(256) void nn_prep(const float* __restrict__ q,
                                               const float* __restrict__ c,
                                               unsigned short* __restrict__ Amat,
                                               unsigned short* __restrict__ Bmat) {
    const int m = blockIdx.x * 256 + (int)threadIdx.x;
    if (m < NA) {
        unsigned short a[16];
        #pragma unroll
        for (int r = 0; r < 16; ++r) a[r] = 0;
        if (m < N_PTS) {
            const float cx = c[m * 3 + 0], cy = c[m * 3 + 1], cz = c[m * 3 + 2];
            const unsigned short hx = f2bf(cx), hy = f2bf(cy), hz = f2bf(cz);
            const float lx = cx - bf2f(hx), ly = cy - bf2f(hy), lz = cz - bf2f(hz);
            const float y2 = fmaf(cx, cx, fmaf(cy, cy, cz * cz));
            const unsigned short y2h = f2bf(y2);
            const unsigned short y2l = f2bf(y2 - bf2f(y2h));
            a[0] = f2bf(-2.f * bf2f(hx)); a[1] = f2bf(-2.f * bf2f(hy)); a[2] = f2bf(-2.f * bf2f(hz));
            a[3] = a[0]; a[4] = a[1]; a[5] = a[2];
            a[6] = f2bf(-2.f * lx); a[7] = f2bf(-2.f * ly); a[8] = f2bf(-2.f * lz);
            a[9] = y2h; a[10] = y2l;
        } else {
            a[9] = f2bf(1e30f);   // padded candidates: huge key, never wins
        }
        unsigned int* o = (unsigned int*)(Amat + (size_t)m * 16);
        #pragma unroll
        for (int r = 0; r < 8; ++r)
            o[r] = (unsigned int)a[2 * r] | ((unsigned int)a[2 * r + 1] << 16);
    }
    if (m < NB) {
        unsigned short b[16];
        #pragma unroll
        for (int r = 0; r < 16; ++r) b[r] = 0;
        if (m < N_PTS) {
            const float qx = q[m * 3 + 0], qy = q[m * 3 + 1], qz = q[m * 3 + 2];
            const unsigned short hx = f2bf(qx), hy = f2bf(qy), hz = f2bf(qz);
            b[0] = hx; b[1] = hy; b[2] = hz;
            b[3] = f2bf(qx - bf2f(hx)); b[4] = f2bf(qy - bf2f(hy)); b[5] = f2bf(qz - bf2f(hz));
            b[6] = hx; b[7] = hy; b[8] = hz;
            b[9] = f2bf(1.0f); b[10] = f2bf(1.0f);
        }
        unsigned int* o = (unsigned int*)(Bmat + (size_t)m * 16);
        #pragma unroll
        for (int r = 0; r < 8; ++r)
            o[r] = (unsigned int)b[2 * r] | ((unsigned int)b[2 * r + 1] << 16);
    }
}

// Each wave: 64 queries (2 B-frags) x one candidate chunk of tpc tiles.
// Running min per acc-reg-slot with tile index packed in low 6 mantissa bits (1 bfi + 1 fmin per reg).
// C/D layout (m74/m101): col=lane&31 (query), row=(reg&3)+8*(reg>>2)+4*(lane>>5) (candidate)
__global__ __launch_bounds__(256, 4) void nn_main(const unsigned short* __restrict__ Amat,
                                                  const unsigned short* __restrict__ Bmat,
                                                  float2* __restrict__ partial,
                                                  int lc) {
    const int C = 1 << lc;
    const int tpc = TILES_TOTAL >> lc;
    const int wid = blockIdx.x * 4 + (int)(threadIdx.x >> 6);
    const int nw = 313 << lc;
    if (wid >= nw) return;
    const int lane = (int)(threadIdx.x & 63);
    const int qg = wid >> lc;
    const int ch = wid & (C - 1);
    const int qbase = qg * 64;
    const int lane31 = lane & 31;
    const int half = lane >> 5;

    const bf16x8 b1 = *(const bf16x8*)(Bmat + (size_t)(qbase + lane31) * 16 + half * 8);
    const bf16x8 b2 = *(const bf16x8*)(Bmat + (size_t)(qbase + 32 + lane31) * 16 + half * 8);

    const f32x16 zacc = {0.f, 0.f, 0.f, 0.f, 0.f, 0.f, 0.f, 0.f,
                         0.f, 0.f, 0.f, 0.f, 0.f, 0.f, 0.f, 0.f};

    float vmin1[16], vmin2[16];
    #pragma unroll
    for (int r = 0; r < 16; ++r) {
        vmin1[r] = __uint_as_float(0x7F800000u);
        vmin2[r] = __uint_as_float(0x7F800000u);
    }

    const unsigned short* Ap = Amat + (size_t)(ch * tpc * 32 + lane31) * 16 + half * 8;
    for (int t = 0; t < tpc; ++t) {
        const bf16x8 af = *(const bf16x8*)Ap;
        Ap += 512;   // 32 rows * 16 shorts
        const f32x16 acc1 = __builtin_amdgcn_mfma_f32_32x32x16_bf16(af, b1, zacc, 0, 0, 0);
        const f32x16 acc2 = __builtin_amdgcn_mfma_f32_32x32x16_bf16(af, b2, zacc, 0, 0, 0);
        const unsigned tu = (unsigned)t;
        #pragma unroll
        for (int r = 0; r < 16; ++r) {
            vmin1[r] = fminf(vmin1[r], __uint_as_float(bfi(0xFFFFFFC0u, __float_as_uint(acc1[r]), tu)));
            vmin2[r] = fminf(vmin2[r], __uint_as_float(bfi(0xFFFFFFC0u, __float_as_uint(acc2[r]), tu)));
        }
    }

    // once-per-wave: insert reg slot into bits [9:6], reduce 16 -> 1, decode
    float w1 = __uint_as_float(0x7F800000u), w2 = w1;
    #pragma unroll
    for (int r = 0; r < 16; ++r) {
        w1 = fminf(w1, __uint_as_float(bfi(0xFFFFFC3Fu, __float_as_uint(vmin1[r]), (unsigned)(r << 6))));
        w2 = fminf(w2, __uint_as_float(bfi(0xFFFFFC3Fu, __float_as_uint(vmin2[r]), (unsigned)(r << 6))));
    }
    unsigned wb1 = __float_as_uint(w1);
    unsigned wb2 = __float_as_uint(w2);
    int r1 = (int)((wb1 >> 6) & 15u), t1 = (int)(wb1 & 63u);
    int r2 = (int)((wb2 >> 6) & 15u), t2 = (int)(wb2 & 63u);
    int idx1 = (ch * tpc + t1) * 32 + (r1 & 3) + 8 * (r1 >> 2) + 4 * half;
    int idx2 = (ch * tpc + t2) * 32 + (r2 & 3) + 8 * (r2 >> 2) + 4 * half;

    // merge the two row-halves (lane ^ 32)
    const float ow1 = __shfl_xor(w1, 32);
    const int oi1 = __shfl_xor(idx1, 32);
    if (ow1 < w1 || (ow1 == w1 && oi1 < idx1)) { w1 = ow1; idx1 = oi1; }
    const float ow2 = __shfl_xor(w2, 32);
    const int oi2 = __shfl_xor(idx2, 32);
    if (ow2 < w2 || (ow2 == w2 && oi2 < idx2)) { w2 = ow2; idx2 = oi2; }

    if (lane < 32) {
        const int q1 = qbase + lane;
        if (q1 < N_PTS) partial[(size_t)q1 * C + ch] = make_float2(w1, __int_as_float(idx1));
        const int q2 = qbase + 32 + lane;
        if (q2 < N_PTS) partial[(size_t)q2 * C + ch] = make_float2(w2, __int_as_float(idx2));
    }
}

// Reduce chunks per query, count mismatches, last block writes the loss.
__global__ __launch_bounds__(256) void nn_reduce(const float2* __restrict__ partial,
                                                 const int* __restrict__ labels,
                                                 unsigned int* __restrict__ count,
                                                 unsigned int* __restrict__ ticket,
                                                 float* __restrict__ out, int C) {
    const int i = blockIdx.x * 256 + (int)threadIdx.x;
    int mism = 0;
    if (i < N_PTS) {
        float best = __uint_as_float(0x7F800000u);
        int bidx = 0;
        for (int c = 0; c < C; ++c) {                       // ascending chunk, strict <
            const float2 p = partial[(size_t)i * C + c];
            if (p.x < best) { best = p.x; bidx = __float_as_int(p.y); }
        }
        mism = (labels[bidx] != labels[i]) ? 1 : 0;
    }
    const unsigned long long msk = __ballot(mism != 0);
    __shared__ unsigned int bsum;
    if (threadIdx.x == 0) bsum = 0;
    __syncthreads();
    if ((threadIdx.x & 63) == 0) atomicAdd(&bsum, (unsigned)__popcll(msk));
    __syncthreads();
    if (threadIdx.x == 0) {
        atomicAdd(count, bsum);
        __threadfence();
        const unsigned t = atomicAdd(ticket, 1u);
        if (t == gridDim.x - 1) {
            __threadfence();
            const unsigned total = atomicAdd(count, 0u);
            out[0] = (float)total / (float)N_PTS;
        }
    }
}

extern "C" void kernel_launch(void* const* d_in, const int* in_sizes, int n_in,
                              void* d_out, int out_size, void* d_ws, size_t ws_size,
                              hipStream_t stream) {
    const float* mean_3d      = (const float*)d_in[0];
    const float* mean_3d_cano = (const float*)d_in[1];
    const int*   segm_labels  = (const int*)d_in[2];
    float* out = (float*)d_out;

    unsigned short* Amat = (unsigned short*)d_ws;                         // 655,360 B
    unsigned short* Bmat = (unsigned short*)((char*)d_ws + 655360);       // 641,024 B
    float2* partial = (float2*)((char*)d_ws + 1310720);

    int lc = 4;                                                           // 16 chunks if ws allows
    while (lc > 0 && 1310720ull + 20000ull * (1ull << lc) * 8ull + 8ull > ws_size) --lc;
    const int C = 1 << lc;
    unsigned int* count = (unsigned int*)((char*)d_ws + 1310720 + 20000ull * (size_t)C * 8ull);

    (void)hipMemsetAsync(count, 0, 2 * sizeof(unsigned int), stream);     // count + ticket
    nn_prep<<<NA / 256, 256, 0, stream>>>(mean_3d, mean_3d_cano, Amat, Bmat);
    const int nw = 313 * C;
    nn_main<<<(nw + 3) / 4, 256, 0, stream>>>(Amat, Bmat, partial, lc);
    nn_reduce<<<(N_PTS + 255) / 256, 256, 0, stream>>>(partial, segm_labels, count, count + 1, out, C);
}

// Round 5
// 55.369 us; speedup vs baseline: 1.2851x; 1.2851x over previous
//
#include <hip/hip_runtime.h>

#define N_PTS 20000
#define NA 20480            // candidates padded to 640 tiles of 32
#define NB 20032            // queries padded to 313 wave-groups of 64
#define TILES_TOTAL 640

typedef __attribute__((ext_vector_type(8))) short bf16x8;
typedef __attribute__((ext_vector_type(16))) float f32x16;

static __device__ __forceinline__ unsigned short f2bf(float f) {
    unsigned int u = __float_as_uint(f);
    unsigned int r = (u + 0x7FFFu + ((u >> 16) & 1u)) >> 16;   // RNE
    return (unsigned short)r;
}
static __device__ __forceinline__ float bf2f(unsigned short h) {
    return __uint_as_float(((unsigned int)h) << 16);
}

// Build MFMA operand matrices.
// A row (candidate m), K=16 slots:
//   slots 0-2: -2*c_hi (pairs q_hi) | 3-5: -2*c_hi (pairs q_lo) | 6-8: -2*c_lo (pairs q_hi)
//   slots 9,10: y2 hi/lo (pair with 1.0)
// => acc ~= ||y||^2 - 2 x.y  (argmin key; x^2 constant per query)
__global__ __launch_bounds__(256) void nn_prep(const float* __restrict__ q,
                                               const float* __restrict__ c,
                                               unsigned short* __restrict__ Amat,
                                               unsigned short* __restrict__ Bmat) {
    const int m = blockIdx.x * 256 + (int)threadIdx.x;
    if (m < NA) {
        unsigned short a[16];
        #pragma unroll
        for (int r = 0; r < 16; ++r) a[r] = 0;
        if (m < N_PTS) {
            const float cx = c[m * 3 + 0], cy = c[m * 3 + 1], cz = c[m * 3 + 2];
            const unsigned short hx = f2bf(cx), hy = f2bf(cy), hz = f2bf(cz);
            const float lx = cx - bf2f(hx), ly = cy - bf2f(hy), lz = cz - bf2f(hz);
            const float y2 = fmaf(cx, cx, fmaf(cy, cy, cz * cz));
            const unsigned short y2h = f2bf(y2);
            const unsigned short y2l = f2bf(y2 - bf2f(y2h));
            a[0] = f2bf(-2.f * bf2f(hx)); a[1] = f2bf(-2.f * bf2f(hy)); a[2] = f2bf(-2.f * bf2f(hz));
            a[3] = a[0]; a[4] = a[1]; a[5] = a[2];
            a[6] = f2bf(-2.f * lx); a[7] = f2bf(-2.f * ly); a[8] = f2bf(-2.f * lz);
            a[9] = y2h; a[10] = y2l;
        } else {
            a[9] = f2bf(1e30f);   // padded candidates: huge key, never wins
        }
        unsigned int* o = (unsigned int*)(Amat + (size_t)m * 16);
        #pragma unroll
        for (int r = 0; r < 8; ++r)
            o[r] = (unsigned int)a[2 * r] | ((unsigned int)a[2 * r + 1] << 16);
    }
    if (m < NB) {
        unsigned short b[16];
        #pragma unroll
        for (int r = 0; r < 16; ++r) b[r] = 0;
        if (m < N_PTS) {
            const float qx = q[m * 3 + 0], qy = q[m * 3 + 1], qz = q[m * 3 + 2];
            const unsigned short hx = f2bf(qx), hy = f2bf(qy), hz = f2bf(qz);
            b[0] = hx; b[1] = hy; b[2] = hz;
            b[3] = f2bf(qx - bf2f(hx)); b[4] = f2bf(qy - bf2f(hy)); b[5] = f2bf(qz - bf2f(hz));
            b[6] = hx; b[7] = hy; b[8] = hz;
            b[9] = f2bf(1.0f); b[10] = f2bf(1.0f);
        }
        unsigned int* o = (unsigned int*)(Bmat + (size_t)m * 16);
        #pragma unroll
        for (int r = 0; r < 8; ++r)
            o[r] = (unsigned int)b[2 * r] | ((unsigned int)b[2 * r + 1] << 16);
    }
}

// plain-C pack: compiler emits v_bfi_b32 (no AGPR round-trip forced)
template<unsigned KEYM, unsigned TAGM>
static __device__ __forceinline__ float packkey(float x, unsigned tag) {
    return __uint_as_float((__float_as_uint(x) & KEYM) | (tag & TAGM));
}

// Each wave: 64 queries (2 B-frags) x one candidate chunk of TPC tiles.
// Running min per acc-reg-slot; tile tag in low mantissa bits; tiles paired for v_min3.
// C/D layout (m74/m101): col=lane&31 (query), row=(reg&3)+8*(reg>>2)+4*(lane>>5) (candidate)
template<int LC>
__global__ __launch_bounds__(256, 2) void nn_main(const unsigned short* __restrict__ Amat,
                                                  const unsigned short* __restrict__ Bmat,
                                                  float2* __restrict__ partial) {
    constexpr int C = 1 << LC;
    constexpr int TPC = TILES_TOTAL >> LC;
    constexpr unsigned TB = (TPC <= 64) ? 6u : (TPC <= 128) ? 7u : (TPC <= 256) ? 8u : 10u;
    constexpr unsigned TAGM = (1u << TB) - 1u;
    constexpr unsigned KEYM = ~TAGM;

    const int wid = blockIdx.x * 4 + (int)(threadIdx.x >> 6);
    if (wid >= (313 << LC)) return;
    const int lane = (int)(threadIdx.x & 63);
    const int qg = wid >> LC;
    const int ch = wid & (C - 1);
    const int qbase = qg * 64;
    const int lane31 = lane & 31;
    const int half = lane >> 5;

    const bf16x8 b1 = *(const bf16x8*)(Bmat + (size_t)(qbase + lane31) * 16 + half * 8);
    const bf16x8 b2 = *(const bf16x8*)(Bmat + (size_t)(qbase + 32 + lane31) * 16 + half * 8);

    const f32x16 zacc = {0.f, 0.f, 0.f, 0.f, 0.f, 0.f, 0.f, 0.f,
                         0.f, 0.f, 0.f, 0.f, 0.f, 0.f, 0.f, 0.f};

    float vmin1[16], vmin2[16];
    #pragma unroll
    for (int r = 0; r < 16; ++r) {
        vmin1[r] = __uint_as_float(0x7F800000u);
        vmin2[r] = __uint_as_float(0x7F800000u);
    }

    const unsigned short* Ap = Amat + (size_t)(ch * TPC * 32 + lane31) * 16 + half * 8;
    #pragma unroll 2
    for (int t = 0; t < TPC; t += 2) {
        const bf16x8 af0 = *(const bf16x8*)Ap;
        const bf16x8 af1 = *(const bf16x8*)(Ap + 512);
        Ap += 1024;                       // 2 tiles * 32 rows * 16 shorts
        const f32x16 a1 = __builtin_amdgcn_mfma_f32_32x32x16_bf16(af0, b1, zacc, 0, 0, 0);
        const f32x16 a2 = __builtin_amdgcn_mfma_f32_32x32x16_bf16(af0, b2, zacc, 0, 0, 0);
        const f32x16 c1 = __builtin_amdgcn_mfma_f32_32x32x16_bf16(af1, b1, zacc, 0, 0, 0);
        const f32x16 c2 = __builtin_amdgcn_mfma_f32_32x32x16_bf16(af1, b2, zacc, 0, 0, 0);
        #pragma unroll
        for (int r = 0; r < 16; ++r) {
            const float p0 = packkey<KEYM, TAGM>(a1[r], (unsigned)t);
            const float p1 = packkey<KEYM, TAGM>(c1[r], (unsigned)(t + 1));
            vmin1[r] = fminf(fminf(vmin1[r], p0), p1);     // -> v_min3_f32
            const float q0 = packkey<KEYM, TAGM>(a2[r], (unsigned)t);
            const float q1 = packkey<KEYM, TAGM>(c2[r], (unsigned)(t + 1));
            vmin2[r] = fminf(fminf(vmin2[r], q0), q1);
        }
    }

    // once-per-wave: 16-way reduce with decoded-index tie-break
    float bv1 = __uint_as_float(0x7F800000u), bv2 = bv1;
    int bi1 = 0x7FFFFFFF, bi2 = 0x7FFFFFFF;
    #pragma unroll
    for (int r = 0; r < 16; ++r) {
        const int row = (r & 3) + 8 * (r >> 2) + 4 * half;
        const int tg1 = (int)(__float_as_uint(vmin1[r]) & TAGM);
        const int id1 = (ch * TPC + tg1) * 32 + row;
        if (vmin1[r] < bv1 || (vmin1[r] == bv1 && id1 < bi1)) { bv1 = vmin1[r]; bi1 = id1; }
        const int tg2 = (int)(__float_as_uint(vmin2[r]) & TAGM);
        const int id2 = (ch * TPC + tg2) * 32 + row;
        if (vmin2[r] < bv2 || (vmin2[r] == bv2 && id2 < bi2)) { bv2 = vmin2[r]; bi2 = id2; }
    }

    // merge the two row-halves (lane ^ 32)
    const float ow1 = __shfl_xor(bv1, 32);
    const int oi1 = __shfl_xor(bi1, 32);
    if (ow1 < bv1 || (ow1 == bv1 && oi1 < bi1)) { bv1 = ow1; bi1 = oi1; }
    const float ow2 = __shfl_xor(bv2, 32);
    const int oi2 = __shfl_xor(bi2, 32);
    if (ow2 < bv2 || (ow2 == bv2 && oi2 < bi2)) { bv2 = ow2; bi2 = oi2; }

    if (lane < 32) {
        const int q1 = qbase + lane;
        if (q1 < N_PTS) partial[(size_t)q1 * C + ch] = make_float2(bv1, __int_as_float(bi1));
        const int q2 = qbase + 32 + lane;
        if (q2 < N_PTS) partial[(size_t)q2 * C + ch] = make_float2(bv2, __int_as_float(bi2));
    }
}

// Reduce chunks per query, count mismatches, last block writes the loss.
__global__ __launch_bounds__(256) void nn_reduce(const float2* __restrict__ partial,
                                                 const int* __restrict__ labels,
                                                 unsigned int* __restrict__ count,
                                                 unsigned int* __restrict__ ticket,
                                                 float* __restrict__ out, int C) {
    const int i = blockIdx.x * 256 + (int)threadIdx.x;
    int mism = 0;
    if (i < N_PTS) {
        float best = __uint_as_float(0x7F800000u);
        int bidx = 0;
        for (int c = 0; c < C; ++c) {                       // ascending chunk, strict <
            const float2 p = partial[(size_t)i * C + c];
            if (p.x < best) { best = p.x; bidx = __float_as_int(p.y); }
        }
        mism = (labels[bidx] != labels[i]) ? 1 : 0;
    }
    const unsigned long long msk = __ballot(mism != 0);
    __shared__ unsigned int bsum;
    if (threadIdx.x == 0) bsum = 0;
    __syncthreads();
    if ((threadIdx.x & 63) == 0) atomicAdd(&bsum, (unsigned)__popcll(msk));
    __syncthreads();
    if (threadIdx.x == 0) {
        atomicAdd(count, bsum);
        __threadfence();
        const unsigned t = atomicAdd(ticket, 1u);
        if (t == gridDim.x - 1) {
            __threadfence();
            const unsigned total = atomicAdd(count, 0u);
            out[0] = (float)total / (float)N_PTS;
        }
    }
}

extern "C" void kernel_launch(void* const* d_in, const int* in_sizes, int n_in,
                              void* d_out, int out_size, void* d_ws, size_t ws_size,
                              hipStream_t stream) {
    const float* mean_3d      = (const float*)d_in[0];
    const float* mean_3d_cano = (const float*)d_in[1];
    const int*   segm_labels  = (const int*)d_in[2];
    float* out = (float*)d_out;

    unsigned short* Amat = (unsigned short*)d_ws;                         // 655,360 B
    unsigned short* Bmat = (unsigned short*)((char*)d_ws + 655360);       // 641,024 B
    float2* partial = (float2*)((char*)d_ws + 1310720);

    int lc = 4;                                                           // 16 chunks if ws allows
    while (lc > 0 && 1310720ull + 20000ull * (1ull << lc) * 8ull + 8ull > ws_size) --lc;
    const int C = 1 << lc;
    unsigned int* count = (unsigned int*)((char*)d_ws + 1310720 + 20000ull * (size_t)C * 8ull);

    (void)hipMemsetAsync(count, 0, 2 * sizeof(unsigned int), stream);     // count + ticket
    nn_prep<<<NA / 256, 256, 0, stream>>>(mean_3d, mean_3d_cano, Amat, Bmat);

    const int nw = 313 * C;
    const int blocks = (nw + 3) / 4;
    switch (lc) {
        case 4: nn_main<4><<<blocks, 256, 0, stream>>>(Amat, Bmat, partial); break;
        case 3: nn_main<3><<<blocks, 256, 0, stream>>>(Amat, Bmat, partial); break;
        case 2: nn_main<2><<<blocks, 256, 0, stream>>>(Amat, Bmat, partial); break;
        case 1: nn_main<1><<<blocks, 256, 0, stream>>>(Amat, Bmat, partial); break;
        default: nn_main<0><<<blocks, 256, 0, stream>>>(Amat, Bmat, partial); break;
    }
    nn_reduce<<<(N_PTS + 255) / 256, 256, 0, stream>>>(partial, segm_labels, count, count + 1, out, C);
}